// Round 2
// baseline (916.271 us; speedup 1.0000x reference)
//
#include <hip/hip_runtime.h>
#include <hip/hip_bf16.h>

#define K 9
#define C 32
#define H 8
#define DV 8
#define DE 64
#define DIN 128
#define KC 288   // K*C
#define HD 64    // H*DV
#define MS 576   // K*HD

// ---- 1. eqnorm scale per (n,c): scaleg = ln1_g[c]/rms_K; xn0c = nf[n,0,c]*scaleg
__global__ void k_eqnorm1(const float* __restrict__ nf, const float* __restrict__ ln1g,
                          float* __restrict__ scaleg, float* __restrict__ xn0c, int Nn){
  int tid = blockIdx.x*blockDim.x + threadIdx.x;
  if (tid >= Nn*C) return;
  int n = tid >> 5, c = tid & 31;
  const float* base = nf + (size_t)n*KC + c;
  float ss = 0.f, v0 = 0.f;
  #pragma unroll
  for (int k = 0; k < K; ++k){ float v = base[k*C]; ss += v*v; if (k==0) v0 = v; }
  float r = ln1g[c] / sqrtf(ss*(1.0f/K) + 1e-6f);
  scaleg[tid] = r;
  xn0c[tid]   = v0 * r;
}

// ---- 2. attention logits -> z=exp(logit) (segment_max skipped: softmax is
// shift-invariant and |logit| <~ 4, exp is safe in f32), denom atomics
__global__ void k_logits(const float* __restrict__ xn0c, const float* __restrict__ ef,
                         const int* __restrict__ src, const int* __restrict__ dst,
                         const float* __restrict__ Wa, const float* __restrict__ ba,
                         float* __restrict__ zbuf, float* __restrict__ denom, int Ee){
  __shared__ float inpL[4][DIN];
  int lane = threadIdx.x & 63, w = threadIdx.x >> 6;
  int e = blockIdx.x*4 + w;
  bool ok = e < Ee;
  int s = 0, d = 0;
  if (ok){ s = src[e]; d = dst[e]; }
  if (ok){
    if (lane < 32) inpL[w][lane] = xn0c[(size_t)s*C + lane];
    else           inpL[w][lane] = xn0c[(size_t)d*C + (lane-32)];
    inpL[w][64+lane] = ef[(size_t)e*DE + lane];
  }
  __syncthreads();
  if (ok){
    int h = lane >> 3, i0 = lane & 7;
    float acc = 0.f;
    #pragma unroll
    for (int i = 0; i < DIN/8; ++i){
      int idx = i*8 + i0;
      acc += inpL[w][idx] * Wa[idx*H + h];
    }
    acc += __shfl_xor(acc, 1);
    acc += __shfl_xor(acc, 2);
    acc += __shfl_xor(acc, 4);
    if (i0 == 0){
      float z = __expf(acc + ba[h]);
      zbuf[(size_t)e*H + h] = z;
      atomicAdd(&denom[(size_t)d*H + h], z);
    }
  }
}

// ---- 3. messages: v = (nf[src]*scaleg[src]) @ Wv, scale by alpha, scatter-add
__global__ void k_msg(const float* __restrict__ nf, const float* __restrict__ scaleg,
                      const float* __restrict__ zbuf, const float* __restrict__ denom,
                      const int* __restrict__ src, const int* __restrict__ dst,
                      const float* __restrict__ Wv, float* __restrict__ msg, int Ee){
  __shared__ float xsL[4][KC];
  int lane = threadIdx.x & 63, w = threadIdx.x >> 6;
  int e = blockIdx.x*4 + w;
  bool ok = e < Ee;
  int s = 0, d0 = 0;
  if (ok){ s = src[e]; d0 = dst[e]; }
  if (ok){
    const float* xb = nf + (size_t)s*KC;
    const float* sb = scaleg + (size_t)s*C;
    for (int i = lane; i < KC; i += 64) xsL[w][i] = xb[i] * sb[i & 31];
  }
  __syncthreads();
  if (!ok) return;
  int dd = lane;           // output dim 0..63
  int h = dd >> 3;
  float alpha = zbuf[(size_t)e*H + h] / (denom[(size_t)d0*H + h] + 1e-9f);
  float wv[C];
  #pragma unroll
  for (int c = 0; c < C; ++c) wv[c] = Wv[c*HD + dd];
  float acc[K];
  #pragma unroll
  for (int k = 0; k < K; ++k) acc[k] = 0.f;
  #pragma unroll
  for (int c = 0; c < C; ++c){
    float wvc = wv[c];
    #pragma unroll
    for (int k = 0; k < K; ++k) acc[k] += xsL[w][k*C + c] * wvc;
  }
  float* mb = msg + (size_t)d0*MS + dd;
  #pragma unroll
  for (int k = 0; k < K; ++k) atomicAdd(&mb[k*HD], acc[k]*alpha);
}

// ---- 4. node update: attn = msg@Wo; x = nf+attn; eqnorm2; gate; FFN; node_out(f32)
__global__ void k_node(const float* __restrict__ nf, const float* __restrict__ msg,
                       const float* __restrict__ Wo, const float* __restrict__ ln2g,
                       const float* __restrict__ Wg, const float* __restrict__ W1,
                       const float* __restrict__ W2,
                       float* __restrict__ out_node, int Nn){
  __shared__ float msgL[8][MS];
  __shared__ float xnL[8][KC];
  __shared__ float fL[8][KC];
  int c = threadIdx.x & 31, s = threadIdx.x >> 5;
  int n = blockIdx.x*8 + s;
  bool ok = n < Nn;
  if (ok){
    const float* mb = msg + (size_t)n*MS;
    for (int i = c; i < MS; i += 32) msgL[s][i] = mb[i];
  }
  __syncthreads();
  float x[K];
  if (ok){
    float a[K];
    #pragma unroll
    for (int k = 0; k < K; ++k) a[k] = 0.f;
    for (int d = 0; d < HD; ++d){
      float wo = Wo[d*C + c];
      #pragma unroll
      for (int k = 0; k < K; ++k) a[k] += msgL[s][k*HD + d] * wo;
    }
    const float* nb = nf + (size_t)n*KC + c;
    float ss = 0.f;
    #pragma unroll
    for (int k = 0; k < K; ++k){ x[k] = nb[k*C] + a[k]; ss += x[k]*x[k]; }
    float r = ln2g[c] / sqrtf(ss*(1.0f/K) + 1e-6f);
    #pragma unroll
    for (int k = 0; k < K; ++k) xnL[s][k*C + c] = x[k]*r;
  }
  __syncthreads();
  if (ok){
    float gacc = 0.f;
    for (int cc = 0; cc < C; ++cc) gacc += xnL[s][cc] * Wg[cc*C + c];
    float gate = gacc / (1.0f + __expf(-gacc));
    float f[K];
    #pragma unroll
    for (int k = 0; k < K; ++k) f[k] = 0.f;
    for (int cc = 0; cc < C; ++cc){
      float w1 = W1[cc*C + c];
      #pragma unroll
      for (int k = 0; k < K; ++k) f[k] += xnL[s][k*C + cc] * w1;
    }
    #pragma unroll
    for (int k = 0; k < K; ++k) fL[s][k*C + c] = f[k]*gate;
  }
  __syncthreads();
  if (ok){
    float o[K];
    #pragma unroll
    for (int k = 0; k < K; ++k) o[k] = 0.f;
    for (int cc = 0; cc < C; ++cc){
      float w2 = W2[cc*C + c];
      #pragma unroll
      for (int k = 0; k < K; ++k) o[k] += fL[s][k*C + cc] * w2;
    }
    float* ob = out_node + (size_t)n*KC + c;
    #pragma unroll
    for (int k = 0; k < K; ++k) ob[k*C] = x[k] + o[k];
  }
}

// ---- 5. edge update MLP + LayerNorm; node row-0 gathered from f32 node_out
__global__ void k_edge(const float* __restrict__ node_out, const float* __restrict__ ef,
                       const int* __restrict__ src, const int* __restrict__ dst,
                       const float* __restrict__ Wf1, const float* __restrict__ bf1,
                       const float* __restrict__ Wf2, const float* __restrict__ bf2,
                       const float* __restrict__ lng, const float* __restrict__ lnb,
                       float* __restrict__ out_edge, int Ee){
  __shared__ float inpL[4][DIN];
  __shared__ float u1L[4][DE];
  int lane = threadIdx.x & 63, w = threadIdx.x >> 6;
  int e = blockIdx.x*4 + w;
  bool ok = e < Ee;
  int s = 0, d0 = 0;
  if (ok){ s = src[e]; d0 = dst[e]; }
  float efv = 0.f;
  if (ok){
    if (lane < 32) inpL[w][lane] = node_out[(size_t)s*KC + lane];
    else           inpL[w][lane] = node_out[(size_t)d0*KC + (lane-32)];
    efv = ef[(size_t)e*DE + lane];
    inpL[w][64+lane] = efv;
  }
  __syncthreads();
  if (ok){
    float acc = bf1[lane];
    for (int i = 0; i < DIN; ++i) acc += inpL[w][i] * Wf1[i*DE + lane];
    u1L[w][lane] = fmaxf(acc, 0.f);
  }
  __syncthreads();
  if (!ok) return;
  float acc2 = bf2[lane];
  for (int j = 0; j < DE; ++j) acc2 += u1L[w][j] * Wf2[j*DE + lane];
  float sum = acc2, sumsq = acc2*acc2;
  #pragma unroll
  for (int off = 32; off > 0; off >>= 1){
    sum   += __shfl_xor(sum, off);
    sumsq += __shfl_xor(sumsq, off);
  }
  float mu = sum * (1.0f/DE);
  float var = fmaxf(sumsq * (1.0f/DE) - mu*mu, 0.f);
  float rstd = 1.0f / sqrtf(var + 1e-5f);
  float y = (acc2 - mu) * rstd * lng[lane] + lnb[lane];
  out_edge[(size_t)e*DE + lane] = efv + y;
}

extern "C" void kernel_launch(void* const* d_in, const int* in_sizes, int n_in,
                              void* d_out, int out_size, void* d_ws, size_t ws_size,
                              hipStream_t stream){
  const float* nf  = (const float*)d_in[0];
  const float* ef  = (const float*)d_in[1];
  const int*   ei  = (const int*)d_in[2];
  const float* Wa  = (const float*)d_in[3];
  const float* ba  = (const float*)d_in[4];
  const float* Wv  = (const float*)d_in[5];
  const float* Wo  = (const float*)d_in[6];
  const float* ln1g= (const float*)d_in[7];
  const float* ln2g= (const float*)d_in[8];
  const float* Wg  = (const float*)d_in[9];
  const float* W1  = (const float*)d_in[10];
  const float* W2  = (const float*)d_in[11];
  const float* Wf1 = (const float*)d_in[12];
  const float* bf1 = (const float*)d_in[13];
  const float* Wf2 = (const float*)d_in[14];
  const float* bf2 = (const float*)d_in[15];
  const float* lng = (const float*)d_in[16];
  const float* lnb = (const float*)d_in[17];

  int Nn = in_sizes[0] / KC;     // 20000
  int Ee = in_sizes[2] / 2;      // 200000
  const int* src = ei;
  const int* dst = ei + Ee;

  float* ws     = (float*)d_ws;
  float* scaleg = ws;                               // N*C
  float* xn0c   = scaleg + (size_t)Nn*C;            // N*C
  float* zbuf   = xn0c   + (size_t)Nn*C;            // E*H
  float* denom  = zbuf   + (size_t)Ee*H;            // N*H
  float* msg    = denom  + (size_t)Nn*H;            // N*MS

  hipMemsetAsync(denom, 0, (size_t)Nn*H*sizeof(float), stream);
  hipMemsetAsync(msg,   0, (size_t)Nn*MS*sizeof(float), stream);

  k_eqnorm1<<<(Nn*C+255)/256, 256, 0, stream>>>(nf, ln1g, scaleg, xn0c, Nn);
  k_logits<<<(Ee+3)/4, 256, 0, stream>>>(xn0c, ef, src, dst, Wa, ba, zbuf, denom, Ee);
  k_msg<<<(Ee+3)/4, 256, 0, stream>>>(nf, scaleg, zbuf, denom, src, dst, Wv, msg, Ee);

  float* out_node = (float*)d_out;
  float* out_edge = out_node + (size_t)Nn*KC;
  k_node<<<(Nn+7)/8, 256, 0, stream>>>(nf, msg, Wo, ln2g, Wg, W1, W2, out_node, Nn);
  k_edge<<<(Ee+3)/4, 256, 0, stream>>>(out_node, ef, src, dst, Wf1, bf1, Wf2, bf2, lng, lnb, out_edge, Ee);
}

// Round 3
// 697.135 us; speedup vs baseline: 1.3143x; 1.3143x over previous
//
#include <hip/hip_runtime.h>
#include <hip/hip_bf16.h>

#define K 9
#define C 32
#define H 8
#define DV 8
#define DE 64
#define DIN 128
#define KC 288   // K*C
#define HD 64    // H*DV
#define MS 576   // K*HD

// ---- 1. eqnorm scale per (n,c): scaleg = ln1_g[c]/rms_K; xn0c = nf[n,0,c]*scaleg
__global__ void k_eqnorm1(const float* __restrict__ nf, const float* __restrict__ ln1g,
                          float* __restrict__ scaleg, float* __restrict__ xn0c, int Nn){
  int tid = blockIdx.x*blockDim.x + threadIdx.x;
  if (tid >= Nn*C) return;
  int n = tid >> 5, c = tid & 31;
  const float* base = nf + (size_t)n*KC + c;
  float ss = 0.f, v0 = 0.f;
  #pragma unroll
  for (int k = 0; k < K; ++k){ float v = base[k*C]; ss += v*v; if (k==0) v0 = v; }
  float r = ln1g[c] / sqrtf(ss*(1.0f/K) + 1e-6f);
  scaleg[tid] = r;
  xn0c[tid]   = v0 * r;
}

// ---- CSR build: count, scan (1 block), scatter
__global__ void k_count(const int* __restrict__ dst, int* __restrict__ counts, int Ee){
  int e = blockIdx.x*blockDim.x + threadIdx.x;
  if (e < Ee) atomicAdd(&counts[dst[e]], 1);
}

__global__ void k_scan(const int* __restrict__ counts, int* __restrict__ rowptr,
                       int* __restrict__ rowpos, int Nn, int Ee){
  __shared__ int part[1024];
  int t = threadIdx.x;
  int cpt = (Nn + 1023) >> 10;
  int base = t*cpt;
  int lsum = 0;
  for (int i = 0; i < cpt; ++i){ int idx = base+i; if (idx < Nn) lsum += counts[idx]; }
  part[t] = lsum; __syncthreads();
  for (int off = 1; off < 1024; off <<= 1){
    int v = (t >= off) ? part[t-off] : 0;
    __syncthreads();
    part[t] += v;
    __syncthreads();
  }
  int run = part[t] - lsum;   // exclusive
  for (int i = 0; i < cpt; ++i){
    int idx = base+i;
    if (idx < Nn){ rowptr[idx] = run; rowpos[idx] = run; run += counts[idx]; }
  }
  if (t == 1023) rowptr[Nn] = Ee;
}

__global__ void k_scatter(const int* __restrict__ src, const int* __restrict__ dst,
                          int* __restrict__ rowpos, int* __restrict__ esrc,
                          int* __restrict__ eidx, int Ee){
  int e = blockIdx.x*blockDim.x + threadIdx.x;
  if (e >= Ee) return;
  int d = dst[e];
  int pos = atomicAdd(&rowpos[d], 1);
  eidx[pos] = e;
  esrc[pos] = src[e];
}

// ---- 2. per-node values V = (nf*scaleg) @ Wv   (wave per node)
__global__ void k_value(const float* __restrict__ nf, const float* __restrict__ scaleg,
                        const float* __restrict__ Wv, float* __restrict__ V, int Nn){
  __shared__ float xsL[4][KC];
  int lane = threadIdx.x & 63, w = threadIdx.x >> 6;
  int n = blockIdx.x*4 + w;
  bool ok = n < Nn;
  if (ok){
    const float* xb = nf + (size_t)n*KC;
    const float* sb = scaleg + (size_t)n*C;
    for (int i = lane; i < KC; i += 64) xsL[w][i] = xb[i]*sb[i & 31];
  }
  __syncthreads();
  if (!ok) return;
  int dd = lane;
  float acc[K];
  #pragma unroll
  for (int k = 0; k < K; ++k) acc[k] = 0.f;
  for (int c = 0; c < C; ++c){
    float wvc = Wv[c*HD + dd];
    #pragma unroll
    for (int k = 0; k < K; ++k) acc[k] += xsL[w][k*C + c] * wvc;
  }
  float* vb = V + (size_t)n*MS + dd;
  #pragma unroll
  for (int k = 0; k < K; ++k) vb[k*HD] = acc[k];
}

// ---- 3. attention z=exp(logit) (segment_max skipped: shift-invariant, |logit| small)
__global__ void k_logits(const float* __restrict__ xn0c, const float* __restrict__ ef,
                         const int* __restrict__ src, const int* __restrict__ dst,
                         const float* __restrict__ Wa, const float* __restrict__ ba,
                         float* __restrict__ zbuf, int Ee){
  __shared__ float inpL[4][DIN];
  int lane = threadIdx.x & 63, w = threadIdx.x >> 6;
  int e = blockIdx.x*4 + w;
  bool ok = e < Ee;
  int s = 0, d = 0;
  if (ok){ s = src[e]; d = dst[e]; }
  if (ok){
    if (lane < 32) inpL[w][lane] = xn0c[(size_t)s*C + lane];
    else           inpL[w][lane] = xn0c[(size_t)d*C + (lane-32)];
    inpL[w][64+lane] = ef[(size_t)e*DE + lane];
  }
  __syncthreads();
  if (ok){
    int h = lane >> 3, i0 = lane & 7;
    float acc = 0.f;
    #pragma unroll
    for (int i = 0; i < DIN/8; ++i){
      int idx = i*8 + i0;
      acc += inpL[w][idx] * Wa[idx*H + h];
    }
    acc += __shfl_xor(acc, 1);
    acc += __shfl_xor(acc, 2);
    acc += __shfl_xor(acc, 4);
    if (i0 == 0) zbuf[(size_t)e*H + h] = __expf(acc + ba[h]);
  }
}

// ---- 4. fused gather + node update (wave per node, 4 nodes/block)
__global__ void k_node(const float* __restrict__ nf, const float* __restrict__ V,
                       const float* __restrict__ zbuf, const int* __restrict__ rowptr,
                       const int* __restrict__ esrc, const int* __restrict__ eidx,
                       const float* __restrict__ Wo, const float* __restrict__ ln2g,
                       const float* __restrict__ Wg, const float* __restrict__ W1,
                       const float* __restrict__ W2, float* __restrict__ out_node, int Nn){
  __shared__ float msgL[4][MS];
  __shared__ float xnL[4][KC];
  __shared__ float fL[4][KC];
  int lane = threadIdx.x & 63, w = threadIdx.x >> 6;
  int n = blockIdx.x*4 + w;
  bool ok = n < Nn;
  if (ok){
    int r0 = rowptr[n], r1 = rowptr[n+1];
    int h = lane >> 3;
    float den = 0.f;
    for (int r = r0; r < r1; ++r){
      int e = eidx[r];
      den += zbuf[(size_t)e*H + h];
    }
    den += 1e-9f;
    float inv = 1.0f / den;
    float acc[K];
    #pragma unroll
    for (int k = 0; k < K; ++k) acc[k] = 0.f;
    for (int r = r0; r < r1; ++r){
      int e = eidx[r];
      int s = esrc[r];
      float alpha = zbuf[(size_t)e*H + h] * inv;
      const float* vb = V + (size_t)s*MS + lane;
      #pragma unroll
      for (int k = 0; k < K; ++k) acc[k] += alpha * vb[k*HD];
    }
    #pragma unroll
    for (int k = 0; k < K; ++k) msgL[w][k*HD + lane] = acc[k];
  }
  __syncthreads();
  int c = lane & 31;
  bool act = ok && (lane < 32);
  float x[K];
  if (act){
    float a[K];
    #pragma unroll
    for (int k = 0; k < K; ++k) a[k] = 0.f;
    for (int d = 0; d < HD; ++d){
      float wo = Wo[d*C + c];
      #pragma unroll
      for (int k = 0; k < K; ++k) a[k] += msgL[w][k*HD + d] * wo;
    }
    const float* nb = nf + (size_t)n*KC + c;
    float ss = 0.f;
    #pragma unroll
    for (int k = 0; k < K; ++k){ x[k] = nb[k*C] + a[k]; ss += x[k]*x[k]; }
    float r = ln2g[c] / sqrtf(ss*(1.0f/K) + 1e-6f);
    #pragma unroll
    for (int k = 0; k < K; ++k) xnL[w][k*C + c] = x[k]*r;
  }
  __syncthreads();
  if (act){
    float gacc = 0.f;
    for (int cc = 0; cc < C; ++cc) gacc += xnL[w][cc] * Wg[cc*C + c];
    float gate = gacc / (1.0f + __expf(-gacc));
    float f[K];
    #pragma unroll
    for (int k = 0; k < K; ++k) f[k] = 0.f;
    for (int cc = 0; cc < C; ++cc){
      float w1 = W1[cc*C + c];
      #pragma unroll
      for (int k = 0; k < K; ++k) f[k] += xnL[w][k*C + cc] * w1;
    }
    #pragma unroll
    for (int k = 0; k < K; ++k) fL[w][k*C + c] = f[k]*gate;
  }
  __syncthreads();
  if (act){
    float o[K];
    #pragma unroll
    for (int k = 0; k < K; ++k) o[k] = 0.f;
    for (int cc = 0; cc < C; ++cc){
      float w2 = W2[cc*C + c];
      #pragma unroll
      for (int k = 0; k < K; ++k) o[k] += fL[w][k*C + cc] * w2;
    }
    float* ob = out_node + (size_t)n*KC + c;
    #pragma unroll
    for (int k = 0; k < K; ++k) ob[k*C] = x[k] + o[k];
  }
}

// ---- 5. edge MLP + LayerNorm, weights staged in LDS, grid-stride
__global__ void k_edge(const float* __restrict__ node_out, const float* __restrict__ ef,
                       const int* __restrict__ src, const int* __restrict__ dst,
                       const float* __restrict__ Wf1, const float* __restrict__ bf1,
                       const float* __restrict__ Wf2, const float* __restrict__ bf2,
                       const float* __restrict__ lng, const float* __restrict__ lnb,
                       float* __restrict__ out_edge, int Ee){
  __shared__ float W1L[DIN*DE];
  __shared__ float W2L[DE*DE];
  __shared__ float bL[4*DE];
  __shared__ float inpL[4][DIN];
  __shared__ float u1L[4][DE];
  int t = threadIdx.x;
  for (int i = t; i < DIN*DE; i += 256) W1L[i] = Wf1[i];
  for (int i = t; i < DE*DE; i += 256)  W2L[i] = Wf2[i];
  if (t < DE){ bL[t] = bf1[t]; bL[64+t] = bf2[t]; bL[128+t] = lng[t]; bL[192+t] = lnb[t]; }
  __syncthreads();
  int lane = t & 63, w = t >> 6;
  int stride = gridDim.x * 4;
  for (int e0 = blockIdx.x*4; e0 < Ee; e0 += stride){
    int e = e0 + w;
    bool ok = e < Ee;
    float efv = 0.f;
    if (ok){
      int s = src[e], d0 = dst[e];
      if (lane < 32) inpL[w][lane] = node_out[(size_t)s*KC + lane];
      else           inpL[w][lane] = node_out[(size_t)d0*KC + (lane-32)];
      efv = ef[(size_t)e*DE + lane];
      inpL[w][64+lane] = efv;
    }
    __syncthreads();
    if (ok){
      float acc = bL[lane];
      for (int i = 0; i < DIN; ++i) acc += inpL[w][i] * W1L[i*DE + lane];
      u1L[w][lane] = fmaxf(acc, 0.f);
    }
    __syncthreads();
    if (ok){
      float acc2 = bL[64+lane];
      for (int j = 0; j < DE; ++j) acc2 += u1L[w][j] * W2L[j*DE + lane];
      float sum = acc2, sumsq = acc2*acc2;
      #pragma unroll
      for (int off = 32; off > 0; off >>= 1){
        sum   += __shfl_xor(sum, off);
        sumsq += __shfl_xor(sumsq, off);
      }
      float mu = sum * (1.0f/DE);
      float var = fmaxf(sumsq * (1.0f/DE) - mu*mu, 0.f);
      float rstd = 1.0f / sqrtf(var + 1e-5f);
      float y = (acc2 - mu) * rstd * bL[128+lane] + bL[192+lane];
      out_edge[(size_t)e*DE + lane] = efv + y;
    }
    __syncthreads();
  }
}

extern "C" void kernel_launch(void* const* d_in, const int* in_sizes, int n_in,
                              void* d_out, int out_size, void* d_ws, size_t ws_size,
                              hipStream_t stream){
  const float* nf  = (const float*)d_in[0];
  const float* ef  = (const float*)d_in[1];
  const int*   ei  = (const int*)d_in[2];
  const float* Wa  = (const float*)d_in[3];
  const float* ba  = (const float*)d_in[4];
  const float* Wv  = (const float*)d_in[5];
  const float* Wo  = (const float*)d_in[6];
  const float* ln1g= (const float*)d_in[7];
  const float* ln2g= (const float*)d_in[8];
  const float* Wg  = (const float*)d_in[9];
  const float* W1  = (const float*)d_in[10];
  const float* W2  = (const float*)d_in[11];
  const float* Wf1 = (const float*)d_in[12];
  const float* bf1 = (const float*)d_in[13];
  const float* Wf2 = (const float*)d_in[14];
  const float* bf2 = (const float*)d_in[15];
  const float* lng = (const float*)d_in[16];
  const float* lnb = (const float*)d_in[17];

  int Nn = in_sizes[0] / KC;     // 20000
  int Ee = in_sizes[2] / 2;      // 200000
  const int* src = ei;
  const int* dst = ei + Ee;

  float* fws    = (float*)d_ws;
  float* scaleg = fws;                              // N*C
  float* xn0c   = scaleg + (size_t)Nn*C;            // N*C
  float* zbuf   = xn0c   + (size_t)Nn*C;            // E*H
  float* V      = zbuf   + (size_t)Ee*H;            // N*MS
  int*   iws    = (int*)(V + (size_t)Nn*MS);
  int*   counts = iws;                              // N
  int*   rowptr = counts + Nn;                      // N+1
  int*   rowpos = rowptr + Nn + 1;                  // N
  int*   eidx   = rowpos + Nn;                      // E
  int*   esrc   = eidx + Ee;                        // E

  hipMemsetAsync(counts, 0, (size_t)Nn*sizeof(int), stream);

  k_eqnorm1<<<(Nn*C+255)/256, 256, 0, stream>>>(nf, ln1g, scaleg, xn0c, Nn);
  k_count  <<<(Ee+255)/256, 256, 0, stream>>>(dst, counts, Ee);
  k_scan   <<<1, 1024, 0, stream>>>(counts, rowptr, rowpos, Nn, Ee);
  k_scatter<<<(Ee+255)/256, 256, 0, stream>>>(src, dst, rowpos, esrc, eidx, Ee);
  k_value  <<<(Nn+3)/4, 256, 0, stream>>>(nf, scaleg, Wv, V, Nn);
  k_logits <<<(Ee+3)/4, 256, 0, stream>>>(xn0c, ef, src, dst, Wa, ba, zbuf, Ee);

  float* out_node = (float*)d_out;
  float* out_edge = out_node + (size_t)Nn*KC;
  k_node<<<(Nn+3)/4, 256, 0, stream>>>(nf, V, zbuf, rowptr, esrc, eidx,
                                       Wo, ln2g, Wg, W1, W2, out_node, Nn);
  k_edge<<<768, 256, 0, stream>>>(out_node, ef, src, dst, Wf1, bf1, Wf2, bf2,
                                  lng, lnb, out_edge, Ee);
}

// Round 4
// 587.848 us; speedup vs baseline: 1.5587x; 1.1859x over previous
//
#include <hip/hip_runtime.h>
#include <hip/hip_bf16.h>

#define K 9
#define C 32
#define H 8
#define DV 8
#define DE 64
#define DIN 128
#define KC 288   // K*C
#define HD 64    // H*DV
#define MS 576   // K*HD

typedef unsigned short u16;

__device__ __forceinline__ float bits2f(u16 b){ return __uint_as_float(((unsigned)b) << 16); }

// ---- 1. eqnorm scale per (n,c): scaleg = ln1_g[c]/rms_K; xn0c = nf[n,0,c]*scaleg
__global__ void k_eqnorm1(const float* __restrict__ nf, const float* __restrict__ ln1g,
                          float* __restrict__ scaleg, float* __restrict__ xn0c, int Nn){
  int tid = blockIdx.x*blockDim.x + threadIdx.x;
  if (tid >= Nn*C) return;
  int n = tid >> 5, c = tid & 31;
  const float* base = nf + (size_t)n*KC + c;
  float ss = 0.f, v0 = 0.f;
  #pragma unroll
  for (int k = 0; k < K; ++k){ float v = base[k*C]; ss += v*v; if (k==0) v0 = v; }
  float r = ln1g[c] / sqrtf(ss*(1.0f/K) + 1e-6f);
  scaleg[tid] = r;
  xn0c[tid]   = v0 * r;
}

// ---- CSR build: count, scan (1 block), scatter
__global__ void k_count(const int* __restrict__ dst, int* __restrict__ counts, int Ee){
  int e = blockIdx.x*blockDim.x + threadIdx.x;
  if (e < Ee) atomicAdd(&counts[dst[e]], 1);
}

__global__ void k_scan(const int* __restrict__ counts, int* __restrict__ rowptr,
                       int* __restrict__ rowpos, int Nn, int Ee){
  __shared__ int part[1024];
  int t = threadIdx.x;
  int cpt = (Nn + 1023) >> 10;
  int base = t*cpt;
  int lsum = 0;
  for (int i = 0; i < cpt; ++i){ int idx = base+i; if (idx < Nn) lsum += counts[idx]; }
  part[t] = lsum; __syncthreads();
  for (int off = 1; off < 1024; off <<= 1){
    int v = (t >= off) ? part[t-off] : 0;
    __syncthreads();
    part[t] += v;
    __syncthreads();
  }
  int run = part[t] - lsum;   // exclusive
  for (int i = 0; i < cpt; ++i){
    int idx = base+i;
    if (idx < Nn){ rowptr[idx] = run; rowpos[idx] = run; run += counts[idx]; }
  }
  if (t == 1023) rowptr[Nn] = Ee;
}

__global__ void k_scatter(const int* __restrict__ src, const int* __restrict__ dst,
                          int* __restrict__ rowpos, int* __restrict__ esrc,
                          int* __restrict__ eidx, int Ee){
  int e = blockIdx.x*blockDim.x + threadIdx.x;
  if (e >= Ee) return;
  int d = dst[e];
  int pos = atomicAdd(&rowpos[d], 1);
  eidx[pos] = e;
  esrc[pos] = src[e];
}

// ---- 2. per-node values V = (nf*scaleg) @ Wv  -> bf16 storage
__global__ void k_value(const float* __restrict__ nf, const float* __restrict__ scaleg,
                        const float* __restrict__ Wv, u16* __restrict__ V, int Nn){
  __shared__ float xsL[4][KC];
  int lane = threadIdx.x & 63, w = threadIdx.x >> 6;
  int n = blockIdx.x*4 + w;
  bool ok = n < Nn;
  if (ok){
    const float* xb = nf + (size_t)n*KC;
    const float* sb = scaleg + (size_t)n*C;
    for (int i = lane; i < KC; i += 64) xsL[w][i] = xb[i]*sb[i & 31];
  }
  __syncthreads();
  if (!ok) return;
  int dd = lane;
  float acc[K];
  #pragma unroll
  for (int k = 0; k < K; ++k) acc[k] = 0.f;
  for (int c = 0; c < C; ++c){
    float wvc = Wv[c*HD + dd];
    #pragma unroll
    for (int k = 0; k < K; ++k) acc[k] += xsL[w][k*C + c] * wvc;
  }
  u16* vb = V + (size_t)n*MS + dd;
  #pragma unroll
  for (int k = 0; k < K; ++k){
    __hip_bfloat16 h = __float2bfloat16(acc[k]);
    vb[k*HD] = *(u16*)&h;
  }
}

// ---- 3. attention z=exp(logit) (segment_max skipped: shift-invariant, |logit| small)
__global__ void k_logits(const float* __restrict__ xn0c, const float* __restrict__ ef,
                         const int* __restrict__ src, const int* __restrict__ dst,
                         const float* __restrict__ Wa, const float* __restrict__ ba,
                         float* __restrict__ zbuf, int Ee){
  __shared__ float inpL[4][DIN];
  int lane = threadIdx.x & 63, w = threadIdx.x >> 6;
  int e = blockIdx.x*4 + w;
  bool ok = e < Ee;
  int s = 0, d = 0;
  if (ok){ s = src[e]; d = dst[e]; }
  if (ok){
    if (lane < 32) inpL[w][lane] = xn0c[(size_t)s*C + lane];
    else           inpL[w][lane] = xn0c[(size_t)d*C + (lane-32)];
    inpL[w][64+lane] = ef[(size_t)e*DE + lane];
  }
  __syncthreads();
  if (ok){
    int h = lane >> 3, i0 = lane & 7;
    float acc = 0.f;
    #pragma unroll
    for (int i = 0; i < DIN/8; ++i){
      int idx = i*8 + i0;
      acc += inpL[w][idx] * Wa[idx*H + h];
    }
    acc += __shfl_xor(acc, 1);
    acc += __shfl_xor(acc, 2);
    acc += __shfl_xor(acc, 4);
    if (i0 == 0) zbuf[(size_t)e*H + h] = __expf(acc + ba[h]);
  }
}

// ---- 4. fused gather + node update (wave per node, 4 nodes/block)
__global__ void k_node(const float* __restrict__ nf, const u16* __restrict__ V,
                       const float* __restrict__ zbuf, const int* __restrict__ rowptr,
                       const int* __restrict__ esrc, const int* __restrict__ eidx,
                       const float* __restrict__ Wo, const float* __restrict__ ln2g,
                       const float* __restrict__ Wg, const float* __restrict__ W1,
                       const float* __restrict__ W2, float* __restrict__ out_node, int Nn){
  __shared__ float msgL[4][MS];
  __shared__ float xnL[4][KC];
  __shared__ float fL[4][KC];
  int lane = threadIdx.x & 63, w = threadIdx.x >> 6;
  int n = blockIdx.x*4 + w;
  bool ok = n < Nn;
  if (ok){
    int r0 = rowptr[n], r1 = rowptr[n+1];
    int h = lane >> 3;
    float den = 0.f;
    for (int r = r0; r < r1; ++r){
      int e = eidx[r];
      den += zbuf[(size_t)e*H + h];
    }
    den += 1e-9f;
    float inv = 1.0f / den;
    float acc[K];
    #pragma unroll
    for (int k = 0; k < K; ++k) acc[k] = 0.f;
    for (int r = r0; r < r1; ++r){
      int e = eidx[r];
      int s = esrc[r];
      float alpha = zbuf[(size_t)e*H + h] * inv;
      const u16* vb = V + (size_t)s*MS + lane;
      #pragma unroll
      for (int k = 0; k < K; ++k) acc[k] += alpha * bits2f(vb[k*HD]);
    }
    #pragma unroll
    for (int k = 0; k < K; ++k) msgL[w][k*HD + lane] = acc[k];
  }
  __syncthreads();
  int c = lane & 31;
  bool act = ok && (lane < 32);
  float x[K];
  if (act){
    float a[K];
    #pragma unroll
    for (int k = 0; k < K; ++k) a[k] = 0.f;
    for (int d = 0; d < HD; ++d){
      float wo = Wo[d*C + c];
      #pragma unroll
      for (int k = 0; k < K; ++k) a[k] += msgL[w][k*HD + d] * wo;
    }
    const float* nb = nf + (size_t)n*KC + c;
    float ss = 0.f;
    #pragma unroll
    for (int k = 0; k < K; ++k){ x[k] = nb[k*C] + a[k]; ss += x[k]*x[k]; }
    float r = ln2g[c] / sqrtf(ss*(1.0f/K) + 1e-6f);
    #pragma unroll
    for (int k = 0; k < K; ++k) xnL[w][k*C + c] = x[k]*r;
  }
  __syncthreads();
  if (act){
    float gacc = 0.f;
    for (int cc = 0; cc < C; ++cc) gacc += xnL[w][cc] * Wg[cc*C + c];
    float gate = gacc / (1.0f + __expf(-gacc));
    float f[K];
    #pragma unroll
    for (int k = 0; k < K; ++k) f[k] = 0.f;
    for (int cc = 0; cc < C; ++cc){
      float w1 = W1[cc*C + c];
      #pragma unroll
      for (int k = 0; k < K; ++k) f[k] += xnL[w][k*C + cc] * w1;
    }
    #pragma unroll
    for (int k = 0; k < K; ++k) fL[w][k*C + c] = f[k]*gate;
  }
  __syncthreads();
  if (act){
    float o[K];
    #pragma unroll
    for (int k = 0; k < K; ++k) o[k] = 0.f;
    for (int cc = 0; cc < C; ++cc){
      float w2 = W2[cc*C + c];
      #pragma unroll
      for (int k = 0; k < K; ++k) o[k] += fL[w][k*C + cc] * w2;
    }
    float* ob = out_node + (size_t)n*KC + c;
    #pragma unroll
    for (int k = 0; k < K; ++k) ob[k*C] = x[k] + o[k];
  }
}

// ---- 5. edge MLP + LayerNorm: weights in VGPRs, input broadcast via v_readlane,
//         zero LDS, 4-way FMA chains. Lane l owns output column l.
__global__ __launch_bounds__(256, 2)
void k_edge(const float* __restrict__ node_out, const float* __restrict__ ef,
            const int* __restrict__ src, const int* __restrict__ dst,
            const float* __restrict__ Wf1, const float* __restrict__ bf1,
            const float* __restrict__ Wf2, const float* __restrict__ bf2,
            const float* __restrict__ lng, const float* __restrict__ lnb,
            float* __restrict__ out_edge, int Ee){
  int lane = threadIdx.x & 63, w = threadIdx.x >> 6;
  float w1r[DIN];
  #pragma unroll
  for (int i = 0; i < DIN; ++i) w1r[i] = Wf1[i*DE + lane];
  float w2r[DE];
  #pragma unroll
  for (int j = 0; j < DE; ++j) w2r[j] = Wf2[j*DE + lane];
  float b1 = bf1[lane], b2 = bf2[lane], g = lng[lane], bb = lnb[lane];
  int stride = gridDim.x*4;
  for (int e = blockIdx.x*4 + w; e < Ee; e += stride){
    int s = src[e], d0 = dst[e];
    int nrow = (lane < 32) ? s : d0;
    float rA = node_out[(size_t)nrow*KC + (lane & 31)];
    float rB = ef[(size_t)e*DE + lane];
    int bA = __float_as_int(rA), bB = __float_as_int(rB);
    float a0 = b1, a1 = 0.f, a2 = 0.f, a3 = 0.f;
    #pragma unroll
    for (int i = 0; i < 64; i += 4){
      a0 = fmaf(__int_as_float(__builtin_amdgcn_readlane(bA, i+0)), w1r[i+0], a0);
      a1 = fmaf(__int_as_float(__builtin_amdgcn_readlane(bA, i+1)), w1r[i+1], a1);
      a2 = fmaf(__int_as_float(__builtin_amdgcn_readlane(bA, i+2)), w1r[i+2], a2);
      a3 = fmaf(__int_as_float(__builtin_amdgcn_readlane(bA, i+3)), w1r[i+3], a3);
    }
    #pragma unroll
    for (int i = 0; i < 64; i += 4){
      a0 = fmaf(__int_as_float(__builtin_amdgcn_readlane(bB, i+0)), w1r[64+i+0], a0);
      a1 = fmaf(__int_as_float(__builtin_amdgcn_readlane(bB, i+1)), w1r[64+i+1], a1);
      a2 = fmaf(__int_as_float(__builtin_amdgcn_readlane(bB, i+2)), w1r[64+i+2], a2);
      a3 = fmaf(__int_as_float(__builtin_amdgcn_readlane(bB, i+3)), w1r[64+i+3], a3);
    }
    float u1 = fmaxf((a0+a1) + (a2+a3), 0.f);
    int bU = __float_as_int(u1);
    float c0 = b2, c1 = 0.f, c2 = 0.f, c3 = 0.f;
    #pragma unroll
    for (int j = 0; j < DE; j += 4){
      c0 = fmaf(__int_as_float(__builtin_amdgcn_readlane(bU, j+0)), w2r[j+0], c0);
      c1 = fmaf(__int_as_float(__builtin_amdgcn_readlane(bU, j+1)), w2r[j+1], c1);
      c2 = fmaf(__int_as_float(__builtin_amdgcn_readlane(bU, j+2)), w2r[j+2], c2);
      c3 = fmaf(__int_as_float(__builtin_amdgcn_readlane(bU, j+3)), w2r[j+3], c3);
    }
    float acc2 = (c0+c1) + (c2+c3);
    float sum = acc2, sumsq = acc2*acc2;
    #pragma unroll
    for (int off = 32; off > 0; off >>= 1){
      sum   += __shfl_xor(sum, off);
      sumsq += __shfl_xor(sumsq, off);
    }
    float mu = sum * (1.0f/DE);
    float var = fmaxf(sumsq * (1.0f/DE) - mu*mu, 0.f);
    float rstd = 1.0f / sqrtf(var + 1e-5f);
    float y = (acc2 - mu) * rstd * g + bb;
    out_edge[(size_t)e*DE + lane] = rB + y;
  }
}

extern "C" void kernel_launch(void* const* d_in, const int* in_sizes, int n_in,
                              void* d_out, int out_size, void* d_ws, size_t ws_size,
                              hipStream_t stream){
  const float* nf  = (const float*)d_in[0];
  const float* ef  = (const float*)d_in[1];
  const int*   ei  = (const int*)d_in[2];
  const float* Wa  = (const float*)d_in[3];
  const float* ba  = (const float*)d_in[4];
  const float* Wv  = (const float*)d_in[5];
  const float* Wo  = (const float*)d_in[6];
  const float* ln1g= (const float*)d_in[7];
  const float* ln2g= (const float*)d_in[8];
  const float* Wg  = (const float*)d_in[9];
  const float* W1  = (const float*)d_in[10];
  const float* W2  = (const float*)d_in[11];
  const float* Wf1 = (const float*)d_in[12];
  const float* bf1 = (const float*)d_in[13];
  const float* Wf2 = (const float*)d_in[14];
  const float* bf2 = (const float*)d_in[15];
  const float* lng = (const float*)d_in[16];
  const float* lnb = (const float*)d_in[17];

  int Nn = in_sizes[0] / KC;     // 20000
  int Ee = in_sizes[2] / 2;      // 200000
  const int* src = ei;
  const int* dst = ei + Ee;

  float* fws    = (float*)d_ws;
  float* scaleg = fws;                              // N*C
  float* xn0c   = scaleg + (size_t)Nn*C;            // N*C
  float* zbuf   = xn0c   + (size_t)Nn*C;            // E*H
  u16*   V      = (u16*)(zbuf + (size_t)Ee*H);      // N*MS bf16
  int*   iws    = (int*)(V + (size_t)Nn*MS);
  int*   counts = iws;                              // N
  int*   rowptr = counts + Nn;                      // N+1
  int*   rowpos = rowptr + Nn + 1;                  // N
  int*   eidx   = rowpos + Nn;                      // E
  int*   esrc   = eidx + Ee;                        // E

  hipMemsetAsync(counts, 0, (size_t)Nn*sizeof(int), stream);

  k_eqnorm1<<<(Nn*C+255)/256, 256, 0, stream>>>(nf, ln1g, scaleg, xn0c, Nn);
  k_count  <<<(Ee+255)/256, 256, 0, stream>>>(dst, counts, Ee);
  k_scan   <<<1, 1024, 0, stream>>>(counts, rowptr, rowpos, Nn, Ee);
  k_scatter<<<(Ee+255)/256, 256, 0, stream>>>(src, dst, rowpos, esrc, eidx, Ee);
  k_value  <<<(Nn+3)/4, 256, 0, stream>>>(nf, scaleg, Wv, V, Nn);
  k_logits <<<(Ee+3)/4, 256, 0, stream>>>(xn0c, ef, src, dst, Wa, ba, zbuf, Ee);

  float* out_node = (float*)d_out;
  float* out_edge = out_node + (size_t)Nn*KC;
  k_node<<<(Nn+3)/4, 256, 0, stream>>>(nf, V, zbuf, rowptr, esrc, eidx,
                                       Wo, ln2g, Wg, W1, W2, out_node, Nn);
  k_edge<<<768, 256, 0, stream>>>(out_node, ef, src, dst, Wf1, bf1, Wf2, bf2,
                                  lng, lnb, out_edge, Ee);
}

// Round 5
// 408.984 us; speedup vs baseline: 2.2404x; 1.4373x over previous
//
#include <hip/hip_runtime.h>
#include <hip/hip_bf16.h>

#define K 9
#define C 32
#define H 8
#define DV 8
#define DE 64
#define DIN 128
#define KC 288   // K*C
#define HD 64    // H*DV
#define MS 576   // K*HD

typedef unsigned short u16;
typedef unsigned int u32;

__device__ __forceinline__ u32 f2bbits(float x){
  __hip_bfloat16 hb = __float2bfloat16(x);
  return (u32)(*reinterpret_cast<unsigned short*>(&hb));
}

// ---- 1. eqnorm scale per (n,c): scaleg = ln1_g[c]/rms_K
__global__ void k_eqnorm1(const float* __restrict__ nf, const float* __restrict__ ln1g,
                          float* __restrict__ scaleg, int Nn){
  int tid = blockIdx.x*blockDim.x + threadIdx.x;
  if (tid >= Nn*C) return;
  int n = tid >> 5, c = tid & 31;
  const float* base = nf + (size_t)n*KC + c;
  float ss = 0.f;
  #pragma unroll
  for (int k = 0; k < K; ++k){ float v = base[k*C]; ss += v*v; }
  scaleg[tid] = ln1g[c] / sqrtf(ss*(1.0f/K) + 1e-6f);
}

// ---- CSR build: count, scan (1 block), scatter
__global__ void k_count(const int* __restrict__ dst, int* __restrict__ counts, int Ee){
  int e = blockIdx.x*blockDim.x + threadIdx.x;
  if (e < Ee) atomicAdd(&counts[dst[e]], 1);
}

__global__ void k_scan(const int* __restrict__ counts, int* __restrict__ rowptr,
                       int* __restrict__ rowpos, int Nn, int Ee){
  __shared__ int part[1024];
  int t = threadIdx.x;
  int cpt = (Nn + 1023) >> 10;
  int base = t*cpt;
  int lsum = 0;
  for (int i = 0; i < cpt; ++i){ int idx = base+i; if (idx < Nn) lsum += counts[idx]; }
  part[t] = lsum; __syncthreads();
  for (int off = 1; off < 1024; off <<= 1){
    int v = (t >= off) ? part[t-off] : 0;
    __syncthreads();
    part[t] += v;
    __syncthreads();
  }
  int run = part[t] - lsum;   // exclusive
  for (int i = 0; i < cpt; ++i){
    int idx = base+i;
    if (idx < Nn){ rowptr[idx] = run; rowpos[idx] = run; run += counts[idx]; }
  }
  if (t == 1023) rowptr[Nn] = Ee;
}

__global__ void k_scatter(const int* __restrict__ src, const int* __restrict__ dst,
                          int* __restrict__ rowpos, int* __restrict__ esrc,
                          int* __restrict__ eidx, int Ee){
  int e = blockIdx.x*blockDim.x + threadIdx.x;
  if (e >= Ee) return;
  int d = dst[e];
  int pos = atomicAdd(&rowpos[d], 1);
  eidx[pos] = e;
  esrc[pos] = src[e];
}

// ---- 2. per-node: V = (nf*scaleg)@Wv packed bf16 [n][5][64]; ps/pd logit halves
__global__ void k_value(const float* __restrict__ nf, const float* __restrict__ scaleg,
                        const float* __restrict__ Wv, const float* __restrict__ Wa,
                        const float* __restrict__ ba,
                        u32* __restrict__ V32, float* __restrict__ psb,
                        float* __restrict__ pdb, int Nn){
  __shared__ float xsL[4][KC];
  int lane = threadIdx.x & 63, w = threadIdx.x >> 6;
  int n = blockIdx.x*4 + w;
  bool ok = n < Nn;
  if (ok){
    const float* xb = nf + (size_t)n*KC;
    const float* sb = scaleg + (size_t)n*C;
    for (int i = lane; i < KC; i += 64) xsL[w][i] = xb[i]*sb[i & 31];
  }
  __syncthreads();
  if (!ok) return;
  int dd = lane;
  float acc[K];
  #pragma unroll
  for (int k = 0; k < K; ++k) acc[k] = 0.f;
  for (int c = 0; c < C; ++c){
    float wvc = Wv[c*HD + dd];
    #pragma unroll
    for (int k = 0; k < K; ++k) acc[k] += xsL[w][k*C + c] * wvc;
  }
  u32* vb = V32 + (size_t)n*320 + dd;
  #pragma unroll
  for (int k2 = 0; k2 < 5; ++k2){
    u32 lo = f2bbits(acc[2*k2]);
    u32 hi = (k2 < 4) ? f2bbits(acc[2*k2+1]) : 0u;
    vb[k2*64] = lo | (hi << 16);
  }
  // ps/pd: 8-lane-group dot over C=32
  int h = lane >> 3, i = lane & 7;
  float ps = 0.f, pd = 0.f;
  #pragma unroll
  for (int t = 0; t < 4; ++t){
    int c = i + t*8;
    float xv = xsL[w][c];
    ps = fmaf(xv, Wa[c*H + h], ps);
    pd = fmaf(xv, Wa[(32+c)*H + h], pd);
  }
  ps += __shfl_xor(ps, 1); pd += __shfl_xor(pd, 1);
  ps += __shfl_xor(ps, 2); pd += __shfl_xor(pd, 2);
  ps += __shfl_xor(ps, 4); pd += __shfl_xor(pd, 4);
  if (i == 0){
    psb[(size_t)n*H + h] = ps + ba[h];
    pdb[(size_t)n*H + h] = pd;
  }
}

// ---- 3. logits: tile of 32 edges/block, ef in LDS, Wa2 column in VGPRs,
//         z = exp(ps[src]+pd[dst]+ef.wa2) (segment_max skipped: shift-invariant)
__global__ __launch_bounds__(256)
void k_logits(const float* __restrict__ ef, const int* __restrict__ src,
              const int* __restrict__ dst, const float* __restrict__ Wa,
              const float* __restrict__ psb, const float* __restrict__ pdb,
              float* __restrict__ zbuf, int Ee){
  __shared__ float efL[32*66];
  int t = threadIdx.x;
  int h = t & 7, es = t >> 3;
  float w2r[64];
  #pragma unroll
  for (int d = 0; d < 64; ++d) w2r[d] = Wa[(64+d)*H + h];
  for (int e0 = blockIdx.x*32; e0 < Ee; e0 += gridDim.x*32){
    #pragma unroll
    for (int u = 0; u < 4; ++u){
      int idx = u*512 + t*2;
      int row = idx >> 6, col = idx & 63;
      if (e0 + row < Ee){
        float2 v = *(const float2*)&ef[(size_t)(e0+row)*DE + col];
        *(float2*)&efL[row*66 + col] = v;
      }
    }
    __syncthreads();
    int e = e0 + es;
    if (e < Ee){
      const float* er = &efL[es*66];
      float a0=0.f, a1=0.f, a2=0.f, a3=0.f;
      #pragma unroll
      for (int d = 0; d < 64; d += 4){
        a0 = fmaf(er[d+0], w2r[d+0], a0);
        a1 = fmaf(er[d+1], w2r[d+1], a1);
        a2 = fmaf(er[d+2], w2r[d+2], a2);
        a3 = fmaf(er[d+3], w2r[d+3], a3);
      }
      int s = src[e], d0 = dst[e];
      float logit = (a0+a1)+(a2+a3) + psb[(size_t)s*H + h] + pdb[(size_t)d0*H + h];
      zbuf[(size_t)e*H + h] = __expf(logit);
    }
    __syncthreads();
  }
}

// ---- 4. fused gather + node update (wave per node, 4 nodes/block)
__global__ void k_node(const float* __restrict__ nf, const u32* __restrict__ V32,
                       const float* __restrict__ zbuf, const int* __restrict__ rowptr,
                       const int* __restrict__ esrc, const int* __restrict__ eidx,
                       const float* __restrict__ Wo, const float* __restrict__ ln2g,
                       const float* __restrict__ Wg, const float* __restrict__ W1,
                       const float* __restrict__ W2, float* __restrict__ out_node, int Nn){
  __shared__ float msgL[4][MS];
  __shared__ float xnL[4][KC];
  __shared__ float fL[4][KC];
  int lane = threadIdx.x & 63, w = threadIdx.x >> 6;
  int n = blockIdx.x*4 + w;
  bool ok = n < Nn;
  if (ok){
    int r0 = rowptr[n], r1 = rowptr[n+1];
    int h = lane >> 3;
    float den = 0.f;
    for (int r = r0; r < r1; ++r){
      int e = eidx[r];
      den += zbuf[(size_t)e*H + h];
    }
    den += 1e-9f;
    float inv = 1.0f / den;
    float acc[K];
    #pragma unroll
    for (int k = 0; k < K; ++k) acc[k] = 0.f;
    for (int r = r0; r < r1; ++r){
      int e = eidx[r];
      int s = esrc[r];
      float alpha = zbuf[(size_t)e*H + h] * inv;
      const u32* vb = V32 + (size_t)s*320 + lane;
      #pragma unroll
      for (int k2 = 0; k2 < 5; ++k2){
        u32 pv = vb[k2*64];
        acc[2*k2] = fmaf(alpha, __uint_as_float(pv << 16), acc[2*k2]);
        if (k2 < 4)
          acc[2*k2+1] = fmaf(alpha, __uint_as_float(pv & 0xffff0000u), acc[2*k2+1]);
      }
    }
    #pragma unroll
    for (int k = 0; k < K; ++k) msgL[w][k*HD + lane] = acc[k];
  }
  __syncthreads();
  int c = lane & 31;
  bool act = ok && (lane < 32);
  float x[K];
  if (act){
    float a[K];
    #pragma unroll
    for (int k = 0; k < K; ++k) a[k] = 0.f;
    for (int d = 0; d < HD; ++d){
      float wo = Wo[d*C + c];
      #pragma unroll
      for (int k = 0; k < K; ++k) a[k] += msgL[w][k*HD + d] * wo;
    }
    const float* nb = nf + (size_t)n*KC + c;
    float ss = 0.f;
    #pragma unroll
    for (int k = 0; k < K; ++k){ x[k] = nb[k*C] + a[k]; ss += x[k]*x[k]; }
    float r = ln2g[c] / sqrtf(ss*(1.0f/K) + 1e-6f);
    #pragma unroll
    for (int k = 0; k < K; ++k) xnL[w][k*C + c] = x[k]*r;
  }
  __syncthreads();
  if (act){
    float gacc = 0.f;
    for (int cc = 0; cc < C; ++cc) gacc += xnL[w][cc] * Wg[cc*C + c];
    float gate = gacc / (1.0f + __expf(-gacc));
    float f[K];
    #pragma unroll
    for (int k = 0; k < K; ++k) f[k] = 0.f;
    for (int cc = 0; cc < C; ++cc){
      float w1 = W1[cc*C + c];
      #pragma unroll
      for (int k = 0; k < K; ++k) f[k] += xnL[w][k*C + cc] * w1;
    }
    #pragma unroll
    for (int k = 0; k < K; ++k) fL[w][k*C + c] = f[k]*gate;
  }
  __syncthreads();
  if (act){
    float o[K];
    #pragma unroll
    for (int k = 0; k < K; ++k) o[k] = 0.f;
    for (int cc = 0; cc < C; ++cc){
      float w2 = W2[cc*C + c];
      #pragma unroll
      for (int k = 0; k < K; ++k) o[k] += fL[w][k*C + cc] * w2;
    }
    float* ob = out_node + (size_t)n*KC + c;
    #pragma unroll
    for (int k = 0; k < K; ++k) ob[k*C] = x[k] + o[k];
  }
}

// ---- 5. edge MLP + LayerNorm: weights in VGPRs, broadcast via readlane, zero LDS
__global__ __launch_bounds__(256, 2)
void k_edge(const float* __restrict__ node_out, const float* __restrict__ ef,
            const int* __restrict__ src, const int* __restrict__ dst,
            const float* __restrict__ Wf1, const float* __restrict__ bf1,
            const float* __restrict__ Wf2, const float* __restrict__ bf2,
            const float* __restrict__ lng, const float* __restrict__ lnb,
            float* __restrict__ out_edge, int Ee){
  int lane = threadIdx.x & 63, w = threadIdx.x >> 6;
  float w1r[DIN];
  #pragma unroll
  for (int i = 0; i < DIN; ++i) w1r[i] = Wf1[i*DE + lane];
  float w2r[DE];
  #pragma unroll
  for (int j = 0; j < DE; ++j) w2r[j] = Wf2[j*DE + lane];
  float b1 = bf1[lane], b2 = bf2[lane], g = lng[lane], bb = lnb[lane];
  int stride = gridDim.x*4;
  for (int e = blockIdx.x*4 + w; e < Ee; e += stride){
    int s = src[e], d0 = dst[e];
    int nrow = (lane < 32) ? s : d0;
    float rA = node_out[(size_t)nrow*KC + (lane & 31)];
    float rB = ef[(size_t)e*DE + lane];
    int bA = __float_as_int(rA), bB = __float_as_int(rB);
    float a0 = b1, a1 = 0.f, a2 = 0.f, a3 = 0.f;
    #pragma unroll
    for (int i = 0; i < 64; i += 4){
      a0 = fmaf(__int_as_float(__builtin_amdgcn_readlane(bA, i+0)), w1r[i+0], a0);
      a1 = fmaf(__int_as_float(__builtin_amdgcn_readlane(bA, i+1)), w1r[i+1], a1);
      a2 = fmaf(__int_as_float(__builtin_amdgcn_readlane(bA, i+2)), w1r[i+2], a2);
      a3 = fmaf(__int_as_float(__builtin_amdgcn_readlane(bA, i+3)), w1r[i+3], a3);
    }
    #pragma unroll
    for (int i = 0; i < 64; i += 4){
      a0 = fmaf(__int_as_float(__builtin_amdgcn_readlane(bB, i+0)), w1r[64+i+0], a0);
      a1 = fmaf(__int_as_float(__builtin_amdgcn_readlane(bB, i+1)), w1r[64+i+1], a1);
      a2 = fmaf(__int_as_float(__builtin_amdgcn_readlane(bB, i+2)), w1r[64+i+2], a2);
      a3 = fmaf(__int_as_float(__builtin_amdgcn_readlane(bB, i+3)), w1r[64+i+3], a3);
    }
    float u1 = fmaxf((a0+a1) + (a2+a3), 0.f);
    int bU = __float_as_int(u1);
    float c0 = b2, c1 = 0.f, c2 = 0.f, c3 = 0.f;
    #pragma unroll
    for (int j = 0; j < DE; j += 4){
      c0 = fmaf(__int_as_float(__builtin_amdgcn_readlane(bU, j+0)), w2r[j+0], c0);
      c1 = fmaf(__int_as_float(__builtin_amdgcn_readlane(bU, j+1)), w2r[j+1], c1);
      c2 = fmaf(__int_as_float(__builtin_amdgcn_readlane(bU, j+2)), w2r[j+2], c2);
      c3 = fmaf(__int_as_float(__builtin_amdgcn_readlane(bU, j+3)), w2r[j+3], c3);
    }
    float acc2 = (c0+c1) + (c2+c3);
    float sum = acc2, sumsq = acc2*acc2;
    #pragma unroll
    for (int off = 32; off > 0; off >>= 1){
      sum   += __shfl_xor(sum, off);
      sumsq += __shfl_xor(sumsq, off);
    }
    float mu = sum * (1.0f/DE);
    float var = fmaxf(sumsq * (1.0f/DE) - mu*mu, 0.f);
    float rstd = 1.0f / sqrtf(var + 1e-5f);
    float y = (acc2 - mu) * rstd * g + bb;
    out_edge[(size_t)e*DE + lane] = rB + y;
  }
}

extern "C" void kernel_launch(void* const* d_in, const int* in_sizes, int n_in,
                              void* d_out, int out_size, void* d_ws, size_t ws_size,
                              hipStream_t stream){
  const float* nf  = (const float*)d_in[0];
  const float* ef  = (const float*)d_in[1];
  const int*   ei  = (const int*)d_in[2];
  const float* Wa  = (const float*)d_in[3];
  const float* ba  = (const float*)d_in[4];
  const float* Wv  = (const float*)d_in[5];
  const float* Wo  = (const float*)d_in[6];
  const float* ln1g= (const float*)d_in[7];
  const float* ln2g= (const float*)d_in[8];
  const float* Wg  = (const float*)d_in[9];
  const float* W1  = (const float*)d_in[10];
  const float* W2  = (const float*)d_in[11];
  const float* Wf1 = (const float*)d_in[12];
  const float* bf1 = (const float*)d_in[13];
  const float* Wf2 = (const float*)d_in[14];
  const float* bf2 = (const float*)d_in[15];
  const float* lng = (const float*)d_in[16];
  const float* lnb = (const float*)d_in[17];

  int Nn = in_sizes[0] / KC;     // 20000
  int Ee = in_sizes[2] / 2;      // 200000
  const int* src = ei;
  const int* dst = ei + Ee;

  float* fws    = (float*)d_ws;
  float* scaleg = fws;                              // N*C
  float* zbuf   = scaleg + (size_t)Nn*C;            // E*H
  float* psb    = zbuf   + (size_t)Ee*H;            // N*H
  float* pdb    = psb    + (size_t)Nn*H;            // N*H
  u32*   V32    = (u32*)(pdb + (size_t)Nn*H);       // N*320
  int*   counts = (int*)(V32 + (size_t)Nn*320);     // N
  int*   rowptr = counts + Nn;                      // N+1
  int*   rowpos = rowptr + Nn + 1;                  // N
  int*   eidx   = rowpos + Nn;                      // E
  int*   esrc   = eidx + Ee;                        // E

  hipMemsetAsync(counts, 0, (size_t)Nn*sizeof(int), stream);

  k_eqnorm1<<<(Nn*C+255)/256, 256, 0, stream>>>(nf, ln1g, scaleg, Nn);
  k_count  <<<(Ee+255)/256, 256, 0, stream>>>(dst, counts, Ee);
  k_scan   <<<1, 1024, 0, stream>>>(counts, rowptr, rowpos, Nn, Ee);
  k_scatter<<<(Ee+255)/256, 256, 0, stream>>>(src, dst, rowpos, esrc, eidx, Ee);
  k_value  <<<(Nn+3)/4, 256, 0, stream>>>(nf, scaleg, Wv, Wa, ba, V32, psb, pdb, Nn);
  k_logits <<<1024, 256, 0, stream>>>(ef, src, dst, Wa, psb, pdb, zbuf, Ee);

  float* out_node = (float*)d_out;
  float* out_edge = out_node + (size_t)Nn*KC;
  k_node<<<(Nn+3)/4, 256, 0, stream>>>(nf, V32, zbuf, rowptr, esrc, eidx,
                                       Wo, ln2g, Wg, W1, W2, out_node, Nn);
  k_edge<<<768, 256, 0, stream>>>(out_node, ef, src, dst, Wf1, bf1, Wf2, bf2,
                                  lng, lnb, out_edge, Ee);
}

// Round 7
// 268.645 us; speedup vs baseline: 3.4107x; 1.5224x over previous
//
#include <hip/hip_runtime.h>
#include <hip/hip_bf16.h>

#define K 9
#define C 32
#define H 8
#define DV 8
#define DE 64
#define DIN 128
#define KC 288   // K*C
#define HD 64    // H*DV
#define MS 576   // K*HD

typedef unsigned short u16;
typedef unsigned int u32;
typedef __fp16 f16;
typedef f16 f16x8 __attribute__((ext_vector_type(8)));
typedef f16 f16x2 __attribute__((ext_vector_type(2)));
typedef float f32x4 __attribute__((ext_vector_type(4)));

__device__ __forceinline__ u32 f2bbits(float x){
  __hip_bfloat16 hb = __float2bfloat16(x);
  return (u32)(*reinterpret_cast<unsigned short*>(&hb));
}

__device__ __forceinline__ f16x8 pack8(float4 a, float4 b){
  union { f16x8 v; f16x2 h[4]; } u;
  u.h[0] = __builtin_amdgcn_cvt_pkrtz(a.x, a.y);
  u.h[1] = __builtin_amdgcn_cvt_pkrtz(a.z, a.w);
  u.h[2] = __builtin_amdgcn_cvt_pkrtz(b.x, b.y);
  u.h[3] = __builtin_amdgcn_cvt_pkrtz(b.z, b.w);
  return u.v;
}

// load B-fragment: 8 consecutive K rows of one column, packed f16
__device__ __forceinline__ f16x8 loadWfrag(const float* __restrict__ W, int k0, int col){
  union { f16x8 v; f16x2 h[4]; } u;
  #pragma unroll
  for (int j = 0; j < 4; ++j){
    float x0 = W[(k0 + 2*j    )*DE + col];
    float x1 = W[(k0 + 2*j + 1)*DE + col];
    u.h[j] = __builtin_amdgcn_cvt_pkrtz(x0, x1);
  }
  return u.v;
}

// ---- 1. eqnorm scale per (n,c): scaleg = ln1_g[c]/rms_K
__global__ void k_eqnorm1(const float* __restrict__ nf, const float* __restrict__ ln1g,
                          float* __restrict__ scaleg, int Nn){
  int tid = blockIdx.x*blockDim.x + threadIdx.x;
  if (tid >= Nn*C) return;
  int n = tid >> 5, c = tid & 31;
  const float* base = nf + (size_t)n*KC + c;
  float ss = 0.f;
  #pragma unroll
  for (int k = 0; k < K; ++k){ float v = base[k*C]; ss += v*v; }
  scaleg[tid] = ln1g[c] / sqrtf(ss*(1.0f/K) + 1e-6f);
}

// ---- CSR build
__global__ void k_count(const int* __restrict__ dst, int* __restrict__ counts, int Ee){
  int e = blockIdx.x*blockDim.x + threadIdx.x;
  if (e < Ee) atomicAdd(&counts[dst[e]], 1);
}

__global__ void k_scan(const int* __restrict__ counts, int* __restrict__ rowptr,
                       int* __restrict__ rowpos, int Nn, int Ee){
  __shared__ int part[1024];
  int t = threadIdx.x;
  int cpt = (Nn + 1023) >> 10;
  int base = t*cpt;
  int lsum = 0;
  for (int i = 0; i < cpt; ++i){ int idx = base+i; if (idx < Nn) lsum += counts[idx]; }
  part[t] = lsum; __syncthreads();
  for (int off = 1; off < 1024; off <<= 1){
    int v = (t >= off) ? part[t-off] : 0;
    __syncthreads();
    part[t] += v;
    __syncthreads();
  }
  int run = part[t] - lsum;
  for (int i = 0; i < cpt; ++i){
    int idx = base+i;
    if (idx < Nn){ rowptr[idx] = run; rowpos[idx] = run; run += counts[idx]; }
  }
  if (t == 1023) rowptr[Nn] = Ee;
}

__global__ void k_scatter(const int* __restrict__ src, const int* __restrict__ dst,
                          int* __restrict__ rowpos, int* __restrict__ esrc,
                          int* __restrict__ eidx, int Ee){
  int e = blockIdx.x*blockDim.x + threadIdx.x;
  if (e >= Ee) return;
  int d = dst[e];
  int pos = atomicAdd(&rowpos[d], 1);
  eidx[pos] = e;
  esrc[pos] = src[e];
}

// ---- 2. per-node: V packed bf16 [n][5][64]; ps/pd logit halves
__global__ void k_value(const float* __restrict__ nf, const float* __restrict__ scaleg,
                        const float* __restrict__ Wv, const float* __restrict__ Wa,
                        const float* __restrict__ ba,
                        u32* __restrict__ V32, float* __restrict__ psb,
                        float* __restrict__ pdb, int Nn){
  __shared__ float xsL[4][KC];
  int lane = threadIdx.x & 63, w = threadIdx.x >> 6;
  int n = blockIdx.x*4 + w;
  bool ok = n < Nn;
  if (ok){
    const float* xb = nf + (size_t)n*KC;
    const float* sb = scaleg + (size_t)n*C;
    for (int i = lane; i < KC; i += 64) xsL[w][i] = xb[i]*sb[i & 31];
  }
  __syncthreads();
  if (!ok) return;
  int dd = lane;
  float acc[K];
  #pragma unroll
  for (int k = 0; k < K; ++k) acc[k] = 0.f;
  for (int c = 0; c < C; ++c){
    float wvc = Wv[c*HD + dd];
    #pragma unroll
    for (int k = 0; k < K; ++k) acc[k] += xsL[w][k*C + c] * wvc;
  }
  u32* vb = V32 + (size_t)n*320 + dd;
  #pragma unroll
  for (int k2 = 0; k2 < 5; ++k2){
    u32 lo = f2bbits(acc[2*k2]);
    u32 hi = (k2 < 4) ? f2bbits(acc[2*k2+1]) : 0u;
    vb[k2*64] = lo | (hi << 16);
  }
  int h = lane >> 3, i = lane & 7;
  float ps = 0.f, pd = 0.f;
  #pragma unroll
  for (int t = 0; t < 4; ++t){
    int c = i + t*8;
    float xv = xsL[w][c];
    ps = fmaf(xv, Wa[c*H + h], ps);
    pd = fmaf(xv, Wa[(32+c)*H + h], pd);
  }
  ps += __shfl_xor(ps, 1); pd += __shfl_xor(pd, 1);
  ps += __shfl_xor(ps, 2); pd += __shfl_xor(pd, 2);
  ps += __shfl_xor(ps, 4); pd += __shfl_xor(pd, 4);
  if (i == 0){
    psb[(size_t)n*H + h] = ps + ba[h];
    pdb[(size_t)n*H + h] = pd;
  }
}

// ---- 3. logits
__global__ __launch_bounds__(256)
void k_logits(const float* __restrict__ ef, const int* __restrict__ src,
              const int* __restrict__ dst, const float* __restrict__ Wa,
              const float* __restrict__ psb, const float* __restrict__ pdb,
              float* __restrict__ zbuf, int Ee){
  __shared__ float efL[32*66];
  int t = threadIdx.x;
  int h = t & 7, es = t >> 3;
  float w2r[64];
  #pragma unroll
  for (int d = 0; d < 64; ++d) w2r[d] = Wa[(64+d)*H + h];
  for (int e0 = blockIdx.x*32; e0 < Ee; e0 += gridDim.x*32){
    #pragma unroll
    for (int u = 0; u < 4; ++u){
      int idx = u*512 + t*2;
      int row = idx >> 6, col = idx & 63;
      if (e0 + row < Ee){
        float2 v = *(const float2*)&ef[(size_t)(e0+row)*DE + col];
        *(float2*)&efL[row*66 + col] = v;
      }
    }
    __syncthreads();
    int e = e0 + es;
    if (e < Ee){
      const float* er = &efL[es*66];
      float a0=0.f, a1=0.f, a2=0.f, a3=0.f;
      #pragma unroll
      for (int d = 0; d < 64; d += 4){
        a0 = fmaf(er[d+0], w2r[d+0], a0);
        a1 = fmaf(er[d+1], w2r[d+1], a1);
        a2 = fmaf(er[d+2], w2r[d+2], a2);
        a3 = fmaf(er[d+3], w2r[d+3], a3);
      }
      int s = src[e], d0 = dst[e];
      float logit = (a0+a1)+(a2+a3) + psb[(size_t)s*H + h] + pdb[(size_t)d0*H + h];
      zbuf[(size_t)e*H + h] = __expf(logit);
    }
    __syncthreads();
  }
}

// ---- 4. fused gather + node update
__global__ void k_node(const float* __restrict__ nf, const u32* __restrict__ V32,
                       const float* __restrict__ zbuf, const int* __restrict__ rowptr,
                       const int* __restrict__ esrc, const int* __restrict__ eidx,
                       const float* __restrict__ Wo, const float* __restrict__ ln2g,
                       const float* __restrict__ Wg, const float* __restrict__ W1,
                       const float* __restrict__ W2, float* __restrict__ out_node, int Nn){
  __shared__ float msgL[4][MS];
  __shared__ float xnL[4][KC];
  __shared__ float fL[4][KC];
  int lane = threadIdx.x & 63, w = threadIdx.x >> 6;
  int n = blockIdx.x*4 + w;
  bool ok = n < Nn;
  if (ok){
    int r0 = rowptr[n], r1 = rowptr[n+1];
    int h = lane >> 3;
    float den = 0.f;
    for (int r = r0; r < r1; ++r){
      int e = eidx[r];
      den += zbuf[(size_t)e*H + h];
    }
    den += 1e-9f;
    float inv = 1.0f / den;
    float acc[K];
    #pragma unroll
    for (int k = 0; k < K; ++k) acc[k] = 0.f;
    for (int r = r0; r < r1; ++r){
      int e = eidx[r];
      int s = esrc[r];
      float alpha = zbuf[(size_t)e*H + h] * inv;
      const u32* vb = V32 + (size_t)s*320 + lane;
      #pragma unroll
      for (int k2 = 0; k2 < 5; ++k2){
        u32 pv = vb[k2*64];
        acc[2*k2] = fmaf(alpha, __uint_as_float(pv << 16), acc[2*k2]);
        if (k2 < 4)
          acc[2*k2+1] = fmaf(alpha, __uint_as_float(pv & 0xffff0000u), acc[2*k2+1]);
      }
    }
    #pragma unroll
    for (int k = 0; k < K; ++k) msgL[w][k*HD + lane] = acc[k];
  }
  __syncthreads();
  int c = lane & 31;
  bool act = ok && (lane < 32);
  float x[K];
  if (act){
    float a[K];
    #pragma unroll
    for (int k = 0; k < K; ++k) a[k] = 0.f;
    for (int d = 0; d < HD; ++d){
      float wo = Wo[d*C + c];
      #pragma unroll
      for (int k = 0; k < K; ++k) a[k] += msgL[w][k*HD + d] * wo;
    }
    const float* nb = nf + (size_t)n*KC + c;
    float ss = 0.f;
    #pragma unroll
    for (int k = 0; k < K; ++k){ x[k] = nb[k*C] + a[k]; ss += x[k]*x[k]; }
    float r = ln2g[c] / sqrtf(ss*(1.0f/K) + 1e-6f);
    #pragma unroll
    for (int k = 0; k < K; ++k) xnL[w][k*C + c] = x[k]*r;
  }
  __syncthreads();
  if (act){
    float gacc = 0.f;
    for (int cc = 0; cc < C; ++cc) gacc += xnL[w][cc] * Wg[cc*C + c];
    float gate = gacc / (1.0f + __expf(-gacc));
    float f[K];
    #pragma unroll
    for (int k = 0; k < K; ++k) f[k] = 0.f;
    for (int cc = 0; cc < C; ++cc){
      float w1 = W1[cc*C + c];
      #pragma unroll
      for (int k = 0; k < K; ++k) f[k] += xnL[w][k*C + cc] * w1;
    }
    #pragma unroll
    for (int k = 0; k < K; ++k) fL[w][k*C + c] = f[k]*gate;
  }
  __syncthreads();
  if (act){
    float o[K];
    #pragma unroll
    for (int k = 0; k < K; ++k) o[k] = 0.f;
    for (int cc = 0; cc < C; ++cc){
      float w2 = W2[cc*C + c];
      #pragma unroll
      for (int k = 0; k < K; ++k) o[k] += fL[w][k*C + cc] * w2;
    }
    float* ob = out_node + (size_t)n*KC + c;
    #pragma unroll
    for (int k = 0; k < K; ++k) ob[k*C] = x[k] + o[k];
  }
}

// ---- 5. edge MLP via MFMA: one wave per 32-edge tile; f16 fragments.
//  layer1: [32x128]@[128x64]+b -> relu -> LDS; layer2: [32x64]@[64x64]+b -> LN -> out
__global__ __launch_bounds__(256, 2)
void k_edge(const float* __restrict__ node_out, const float* __restrict__ ef,
            const int* __restrict__ src, const int* __restrict__ dst,
            const float* __restrict__ Wf1, const float* __restrict__ bf1,
            const float* __restrict__ Wf2, const float* __restrict__ bf2,
            const float* __restrict__ lng, const float* __restrict__ lnb,
            float* __restrict__ out_edge, int Ee){
  __shared__ f16 ou1[4][32*72];        // per-wave [32 rows][72 f16] (144B rows, 16B aligned)
  int lane = threadIdx.x & 63, w = threadIdx.x >> 6;
  int g = lane >> 4, c = lane & 15;

  // preload weight fragments (resident across grid-stride loop)
  f16x8 bw1[4][4];                     // [kstep][ntile], layer1 K=128
  #pragma unroll
  for (int t = 0; t < 4; ++t)
    #pragma unroll
    for (int n = 0; n < 4; ++n)
      bw1[t][n] = loadWfrag(Wf1, 32*t + 8*g, 16*n + c);
  f16x8 bw2[2][4];                     // layer2 K=64
  #pragma unroll
  for (int t = 0; t < 2; ++t)
    #pragma unroll
    for (int n = 0; n < 4; ++n)
      bw2[t][n] = loadWfrag(Wf2, 32*t + 8*g, 16*n + c);
  float b1v[4], b2v[4], gv[4], bv[4];
  #pragma unroll
  for (int n = 0; n < 4; ++n){
    b1v[n] = bf1[16*n+c]; b2v[n] = bf2[16*n+c];
    gv[n]  = lng[16*n+c]; bv[n]  = lnb[16*n+c];
  }

  f16* o1 = &ou1[w][0];
  int ntile = (Ee + 31) >> 5;
  for (int tb = blockIdx.x*4 + w; tb < ntile; tb += gridDim.x*4){
    int e0 = tb*32;
    int eA0 = min(e0 + c,      Ee-1);   // row c      (m=0)
    int eA1 = min(e0 + 16 + c, Ee-1);   // row 16+c   (m=1)
    int s0 = src[eA0], s1 = src[eA1], d0 = dst[eA0], d1 = dst[eA1];

    f32x4 acc[2][4];
    #pragma unroll
    for (int m = 0; m < 2; ++m)
      #pragma unroll
      for (int n = 0; n < 4; ++n)
        acc[m][n] = f32x4{b1v[n], b1v[n], b1v[n], b1v[n]};

    // t=0: src rows, k 0..31 ; t=1: dst rows ; t=2/3: ef cols 0..31 / 32..63
    {
      const float* p0 = node_out + (size_t)s0*KC + 8*g;
      const float* p1 = node_out + (size_t)s1*KC + 8*g;
      f16x8 a0 = pack8(*(const float4*)p0, *(const float4*)(p0+4));
      f16x8 a1 = pack8(*(const float4*)p1, *(const float4*)(p1+4));
      #pragma unroll
      for (int n = 0; n < 4; ++n){
        acc[0][n] = __builtin_amdgcn_mfma_f32_16x16x32_f16(a0, bw1[0][n], acc[0][n], 0, 0, 0);
        acc[1][n] = __builtin_amdgcn_mfma_f32_16x16x32_f16(a1, bw1[0][n], acc[1][n], 0, 0, 0);
      }
    }
    {
      const float* p0 = node_out + (size_t)d0*KC + 8*g;
      const float* p1 = node_out + (size_t)d1*KC + 8*g;
      f16x8 a0 = pack8(*(const float4*)p0, *(const float4*)(p0+4));
      f16x8 a1 = pack8(*(const float4*)p1, *(const float4*)(p1+4));
      #pragma unroll
      for (int n = 0; n < 4; ++n){
        acc[0][n] = __builtin_amdgcn_mfma_f32_16x16x32_f16(a0, bw1[1][n], acc[0][n], 0, 0, 0);
        acc[1][n] = __builtin_amdgcn_mfma_f32_16x16x32_f16(a1, bw1[1][n], acc[1][n], 0, 0, 0);
      }
    }
    #pragma unroll
    for (int t = 2; t < 4; ++t){
      int koff = (t-2)*32 + 8*g;
      const float* p0 = ef + (size_t)eA0*DE + koff;
      const float* p1 = ef + (size_t)eA1*DE + koff;
      f16x8 a0 = pack8(*(const float4*)p0, *(const float4*)(p0+4));
      f16x8 a1 = pack8(*(const float4*)p1, *(const float4*)(p1+4));
      #pragma unroll
      for (int n = 0; n < 4; ++n){
        acc[0][n] = __builtin_amdgcn_mfma_f32_16x16x32_f16(a0, bw1[t][n], acc[0][n], 0, 0, 0);
        acc[1][n] = __builtin_amdgcn_mfma_f32_16x16x32_f16(a1, bw1[t][n], acc[1][n], 0, 0, 0);
      }
    }

    // relu -> f16 -> LDS (C/D layout: row=16m+4g+reg, col=16n+c)
    #pragma unroll
    for (int m = 0; m < 2; ++m)
      #pragma unroll
      for (int n = 0; n < 4; ++n)
        #pragma unroll
        for (int r = 0; r < 4; ++r)
          o1[(16*m + 4*g + r)*72 + 16*n + c] = (f16)fmaxf(acc[m][n][r], 0.f);
    asm volatile("s_waitcnt lgkmcnt(0)" ::: "memory");   // wave-internal LDS RAW fence

    // layer 2
    f32x4 acc2[2][4];
    #pragma unroll
    for (int m = 0; m < 2; ++m)
      #pragma unroll
      for (int n = 0; n < 4; ++n)
        acc2[m][n] = f32x4{b2v[n], b2v[n], b2v[n], b2v[n]};
    #pragma unroll
    for (int t = 0; t < 2; ++t){
      f16x8 a20 = *(const f16x8*)(o1 + (     c)*72 + 32*t + 8*g);
      f16x8 a21 = *(const f16x8*)(o1 + (16 + c)*72 + 32*t + 8*g);
      #pragma unroll
      for (int n = 0; n < 4; ++n){
        acc2[0][n] = __builtin_amdgcn_mfma_f32_16x16x32_f16(a20, bw2[t][n], acc2[0][n], 0, 0, 0);
        acc2[1][n] = __builtin_amdgcn_mfma_f32_16x16x32_f16(a21, bw2[t][n], acc2[1][n], 0, 0, 0);
      }
    }

    // LayerNorm per row + residual + store
    #pragma unroll
    for (int m = 0; m < 2; ++m){
      #pragma unroll
      for (int r = 0; r < 4; ++r){
        float s = 0.f, q = 0.f;
        #pragma unroll
        for (int n = 0; n < 4; ++n){ float v = acc2[m][n][r]; s += v; q += v*v; }
        s += __shfl_xor(s, 1);  q += __shfl_xor(q, 1);
        s += __shfl_xor(s, 2);  q += __shfl_xor(q, 2);
        s += __shfl_xor(s, 4);  q += __shfl_xor(q, 4);
        s += __shfl_xor(s, 8);  q += __shfl_xor(q, 8);
        float mu = s * (1.0f/DE);
        float var = fmaxf(q * (1.0f/DE) - mu*mu, 0.f);
        float rstd = 1.0f / sqrtf(var + 1e-5f);
        int e = e0 + 16*m + 4*g + r;
        if (e < Ee){
          #pragma unroll
          for (int n = 0; n < 4; ++n){
            float y = (acc2[m][n][r] - mu) * rstd * gv[n] + bv[n];
            size_t off = (size_t)e*DE + 16*n + c;
            out_edge[off] = ef[off] + y;
          }
        }
      }
    }
  }
}

extern "C" void kernel_launch(void* const* d_in, const int* in_sizes, int n_in,
                              void* d_out, int out_size, void* d_ws, size_t ws_size,
                              hipStream_t stream){
  const float* nf  = (const float*)d_in[0];
  const float* ef  = (const float*)d_in[1];
  const int*   ei  = (const int*)d_in[2];
  const float* Wa  = (const float*)d_in[3];
  const float* ba  = (const float*)d_in[4];
  const float* Wv  = (const float*)d_in[5];
  const float* Wo  = (const float*)d_in[6];
  const float* ln1g= (const float*)d_in[7];
  const float* ln2g= (const float*)d_in[8];
  const float* Wg  = (const float*)d_in[9];
  const float* W1  = (const float*)d_in[10];
  const float* W2  = (const float*)d_in[11];
  const float* Wf1 = (const float*)d_in[12];
  const float* bf1 = (const float*)d_in[13];
  const float* Wf2 = (const float*)d_in[14];
  const float* bf2 = (const float*)d_in[15];
  const float* lng = (const float*)d_in[16];
  const float* lnb = (const float*)d_in[17];

  int Nn = in_sizes[0] / KC;     // 20000
  int Ee = in_sizes[2] / 2;      // 200000
  const int* src = ei;
  const int* dst = ei + Ee;

  float* fws    = (float*)d_ws;
  float* scaleg = fws;                              // N*C
  float* zbuf   = scaleg + (size_t)Nn*C;            // E*H
  float* psb    = zbuf   + (size_t)Ee*H;            // N*H
  float* pdb    = psb    + (size_t)Nn*H;            // N*H
  u32*   V32    = (u32*)(pdb + (size_t)Nn*H);       // N*320
  int*   counts = (int*)(V32 + (size_t)Nn*320);     // N
  int*   rowptr = counts + Nn;                      // N+1
  int*   rowpos = rowptr + Nn + 1;                  // N
  int*   eidx   = rowpos + Nn;                      // E
  int*   esrc   = eidx + Ee;                        // E

  hipMemsetAsync(counts, 0, (size_t)Nn*sizeof(int), stream);

  k_eqnorm1<<<(Nn*C+255)/256, 256, 0, stream>>>(nf, ln1g, scaleg, Nn);
  k_count  <<<(Ee+255)/256, 256, 0, stream>>>(dst, counts, Ee);
  k_scan   <<<1, 1024, 0, stream>>>(counts, rowptr, rowpos, Nn, Ee);
  k_scatter<<<(Ee+255)/256, 256, 0, stream>>>(src, dst, rowpos, esrc, eidx, Ee);
  k_value  <<<(Nn+3)/4, 256, 0, stream>>>(nf, scaleg, Wv, Wa, ba, V32, psb, pdb, Nn);
  k_logits <<<1024, 256, 0, stream>>>(ef, src, dst, Wa, psb, pdb, zbuf, Ee);

  float* out_node = (float*)d_out;
  float* out_edge = out_node + (size_t)Nn*KC;
  k_node<<<(Nn+3)/4, 256, 0, stream>>>(nf, V32, zbuf, rowptr, esrc, eidx,
                                       Wo, ln2g, Wg, W1, W2, out_node, Nn);
  k_edge<<<512, 256, 0, stream>>>(out_node, ef, src, dst, Wf1, bf1, Wf2, bf2,
                                  lng, lnb, out_edge, Ee);
}